// Round 4
// baseline (521201.514 us; speedup 1.0000x reference)
//
#include <hip/hip_runtime.h>
#include <stdint.h>

#define NB    64
#define NN    131072
#define NPTS  1024
#define WPB   4                    // workgroups per batch
#define TPB   512                  // 8 waves
#define NWAVE (TPB / 64)
#define CHUNK (NN / WPB)           // 32768 points per wg
#define PPT   (CHUNK / TPB)        // 64 points per thread
#define RPTS  40                   // register-resident points/thread (j in [0,40))
#define GPTS  14                   // L2-streamed points/thread      (j in [40,54))
#define LPTS  10                   // LDS-resident points/thread     (j in [54,64))
#define RPAIR (RPTS / 2)
#define GPAIR (GPTS / 2)
#define LPAIR (LPTS / 2)

typedef float v2f __attribute__((ext_vector_type(2)));
typedef unsigned long long u64;

static __device__ __forceinline__ v2f vmin2(v2f a, v2f b) {
#if __has_builtin(__builtin_elementwise_min)
    return __builtin_elementwise_min(a, b);
#else
    v2f r; r.x = fminf(a.x, b.x); r.y = fminf(a.y, b.y); return r;
#endif
}

// Key word: [dist_bits:32 | inv_idx:17 (=NN-1-idx) | 0:5 | epoch:10 (=k)]
//   u64 max == (max dist, then min idx); same-round keys share epoch bits so
//   ordering is exact; epoch==k gates the spin (no memset, no ABA: slot for
//   bank k&1 is only rewritten at k+2, provably after all round-k readers —
//   release publish orders the prior spin-loads, acquire spin orders later writes).
// Slot layout per (batch, bank, rank): w0=(x,y) w1=(z,0) w2=key. 32 u64/batch.

__global__ __launch_bounds__(TPB, 2) void fps_kernel(
    const float* __restrict__ pos,
    const int*   __restrict__ start_p,
    int*         __restrict__ out,
    u64*         __restrict__ slots)
{
#pragma clang fp contract(off)
    const int wg   = blockIdx.x;
    const int xcd  = wg & 7;            // heuristic: keep a batch's 4 wgs on one XCD
    const int sl   = wg >> 3;
    const int b    = xcd * 8 + (sl >> 2);
    const int r    = sl & 3;
    const int t    = threadIdx.x;
    const int lane = t & 63;
    const int wv   = t >> 6;

    const float* __restrict__ P  = pos + (size_t)b * NN * 3;
    const float* __restrict__ Pc = P + (size_t)r * CHUNK * 3;
    u64* __restrict__ bslots = slots + (size_t)b * 32;

    __shared__ float ldsP[LPTS * TPB * 3];     // 61440 B
    __shared__ u64   wred[2][NWAVE];           // banked by k&1 (one-barrier loop)

    // ---- one-time staging: j<40 -> regs, j in [54,64) -> LDS (own-thread only) ----
    v2f rx[RPAIR], ry[RPAIR], rz[RPAIR];
#pragma unroll
    for (int p = 0; p < RPAIR; ++p) {
        const float* a = Pc + (size_t)(t + (2 * p) * TPB) * 3;
        const float* c = a + (size_t)TPB * 3;
        rx[p] = (v2f){a[0], c[0]};
        ry[p] = (v2f){a[1], c[1]};
        rz[p] = (v2f){a[2], c[2]};
    }
#pragma unroll
    for (int jl = 0; jl < LPTS; ++jl) {
        const float* a = Pc + (size_t)(t + (RPTS + GPTS + jl) * TPB) * 3;
        float* d = &ldsP[(size_t)(t + jl * TPB) * 3];
        d[0] = a[0]; d[1] = a[1]; d[2] = a[2];   // same-thread RAW only: no barrier
    }

    const int start = start_p[0];
    float sx = P[(size_t)start * 3 + 0];
    float sy = P[(size_t)start * 3 + 1];
    float sz = P[(size_t)start * 3 + 2];
    if (r == 0 && t == 0) out[(size_t)b * NPTS] = start;

    v2f dist[PPT / 2];
#pragma unroll
    for (int p = 0; p < PPT / 2; ++p)
        dist[p] = (v2f){__builtin_inff(), __builtin_inff()};

    const int gbase = r * CHUNK;

    for (int k = 1; k < NPTS; ++k) {
        const int bank = k & 1;
        const v2f s0 = (v2f){sx, sx}, s1 = (v2f){sy, sy}, s2 = (v2f){sz, sz};
        float best = -1.0f;
        int   bi   = 0;

        v2f gx[GPAIR], gy[GPAIR], gz[GPAIR];
#pragma unroll
        for (int q = 0; q < 4; ++q) {           // issue first streamed loads early
            const float* a = Pc + (size_t)(t + (RPTS + 2 * q) * TPB) * 3;
            const float* c = a + (size_t)TPB * 3;
            gx[q] = (v2f){a[0], c[0]};
            gy[q] = (v2f){a[1], c[1]};
            gz[q] = (v2f){a[2], c[2]};
        }

        // exact per-op rounding: (dx*dx + dy*dy) + dz*dz, contract off
#define PAIR_STEP(DP, PX, PY, PZ, I0)                                    \
        {                                                                \
            v2f dx = (PX) - s0, dy = (PY) - s1, dz = (PZ) - s2;          \
            v2f d  = (dx * dx + dy * dy) + dz * dz;                      \
            v2f nd = vmin2(dist[DP], d);                                 \
            dist[DP] = nd;                                               \
            if (nd.x > best) { best = nd.x; bi = (I0); }                 \
            if (nd.y > best) { best = nd.y; bi = (I0) + TPB; }           \
        }

#pragma unroll
        for (int p = 0; p < 10; ++p)
            PAIR_STEP(p, rx[p], ry[p], rz[p], gbase + t + (2 * p) * TPB);
#pragma unroll
        for (int q = 4; q < GPAIR; ++q) {       // issue remaining streamed loads
            const float* a = Pc + (size_t)(t + (RPTS + 2 * q) * TPB) * 3;
            const float* c = a + (size_t)TPB * 3;
            gx[q] = (v2f){a[0], c[0]};
            gy[q] = (v2f){a[1], c[1]};
            gz[q] = (v2f){a[2], c[2]};
        }
#pragma unroll
        for (int p = 10; p < RPAIR; ++p)
            PAIR_STEP(p, rx[p], ry[p], rz[p], gbase + t + (2 * p) * TPB);
#pragma unroll
        for (int q = 0; q < GPAIR; ++q)
            PAIR_STEP(RPAIR + q, gx[q], gy[q], gz[q],
                      gbase + t + (RPTS + 2 * q) * TPB);
#pragma unroll
        for (int l = 0; l < LPAIR; ++l) {
            const int li0 = (t + (2 * l) * TPB) * 3;
            const int li1 = li0 + TPB * 3;
            v2f px = (v2f){ldsP[li0 + 0], ldsP[li1 + 0]};
            v2f py = (v2f){ldsP[li0 + 1], ldsP[li1 + 1]};
            v2f pz = (v2f){ldsP[li0 + 2], ldsP[li1 + 2]};
            PAIR_STEP(RPAIR + GPAIR + l, px, py, pz,
                      gbase + t + (RPTS + GPTS + 2 * l) * TPB);
        }
#undef PAIR_STEP

        const u64 pk0 = ((u64)__float_as_uint(best) << 32) |
                        ((u64)(unsigned)(NN - 1 - bi) << 10) |
                        (unsigned)k;

        u64 pk = pk0;
#pragma unroll
        for (int o = 32; o >= 1; o >>= 1) {
            u64 q = __shfl_xor(pk, o, 64);
            if (q > pk) pk = q;
        }
        if (lane == 0) wred[bank][wv] = pk;
        __syncthreads();

        u64 v = wred[bank][lane & (NWAVE - 1)];
#pragma unroll
        for (int o = 1; o < NWAVE; o <<= 1) {
            u64 q = __shfl_xor(v, o, 64);
            if (q > v) v = q;
        }

        // Unique wg-winning thread extracts coords (regs/L2/LDS) and publishes.
        if (pk0 == v) {
            const int j = (bi - gbase - t) >> 9;   // TPB = 512
            float wx = 0.f, wy = 0.f, wz = 0.f;
            if (j < RPTS) {
#pragma unroll
                for (int p = 0; p < RPAIR; ++p) {
                    if (j == 2 * p)     { wx = rx[p].x; wy = ry[p].x; wz = rz[p].x; }
                    if (j == 2 * p + 1) { wx = rx[p].y; wy = ry[p].y; wz = rz[p].y; }
                }
            } else if (j < RPTS + GPTS) {
                const float* a = Pc + (size_t)(t + j * TPB) * 3;  // L2-hot slice
                wx = a[0]; wy = a[1]; wz = a[2];
            } else {
                const int off = (t + (j - (RPTS + GPTS)) * TPB) * 3;
                wx = ldsP[off]; wy = ldsP[off + 1]; wz = ldsP[off + 2];
            }
            u64* sb = bslots + (size_t)bank * 16 + (size_t)r * 4;
            const u64 w0 = ((u64)__float_as_uint(wx) << 32) | __float_as_uint(wy);
            const u64 w1 = ((u64)__float_as_uint(wz) << 32);
            __hip_atomic_store(sb + 0, w0,  __ATOMIC_RELAXED, __HIP_MEMORY_SCOPE_AGENT);
            __hip_atomic_store(sb + 1, w1,  __ATOMIC_RELAXED, __HIP_MEMORY_SCOPE_AGENT);
            __hip_atomic_store(sb + 2, pk0, __ATOMIC_RELEASE, __HIP_MEMORY_SCOPE_AGENT);
        }

        // all lanes spin: lane L polls rank (L&3)'s key word until epoch == k
        const u64* sp = bslots + (size_t)bank * 16 + (size_t)(lane & 3) * 4;
        u64 g2;
        for (;;) {
            g2 = __hip_atomic_load(sp + 2, __ATOMIC_ACQUIRE, __HIP_MEMORY_SCOPE_AGENT);
            if ((unsigned)(g2 & 1023ull) == (unsigned)k) break;
            __builtin_amdgcn_s_sleep(1);
        }
        u64 a0 = __hip_atomic_load(sp + 0, __ATOMIC_RELAXED, __HIP_MEMORY_SCOPE_AGENT);
        u64 a1 = __hip_atomic_load(sp + 1, __ATOMIC_RELAXED, __HIP_MEMORY_SCOPE_AGENT);

        // combine the 4 ranks: key-compare butterfly carrying the coord payload
#pragma unroll
        for (int o = 1; o <= 2; o <<= 1) {
            u64 qk = __shfl_xor(g2, o, 64);
            u64 q0 = __shfl_xor(a0, o, 64);
            u64 q1 = __shfl_xor(a1, o, 64);
            if (qk > g2) { g2 = qk; a0 = q0; a1 = q1; }
        }

        const int widx = NN - 1 - (int)((g2 >> 10) & 0x1FFFFull);
        if (r == 0 && t == 0) out[(size_t)b * NPTS + k] = widx;
        sx = __uint_as_float((unsigned)(a0 >> 32));
        sy = __uint_as_float((unsigned)a0);
        sz = __uint_as_float((unsigned)(a1 >> 32));
    }
}

extern "C" void kernel_launch(void* const* d_in, const int* in_sizes, int n_in,
                              void* d_out, int out_size, void* d_ws, size_t ws_size,
                              hipStream_t stream)
{
    const float* pos     = (const float*)d_in[0];
    const int*   start_p = (const int*)d_in[1];
    int*         out     = (int*)d_out;
    u64*         slots   = (u64*)d_ws;   // 64 batches x 32 u64 = 16 KB; epoch-tagged, no memset

    void* args[] = { (void*)&pos, (void*)&start_p, (void*)&out, (void*)&slots };
    hipError_t e = hipLaunchCooperativeKernel((const void*)fps_kernel,
                                              dim3(NB * WPB), dim3(TPB),
                                              args, 0, stream);
    if (e != hipSuccess) {
        // 256 blocks of 512 thr = 1 block/CU: de-facto co-resident; same protocol.
        fps_kernel<<<dim3(NB * WPB), dim3(TPB), 0, stream>>>(pos, start_p, out, slots);
    }
}

// Round 5
// 11955.578 us; speedup vs baseline: 43.5948x; 43.5948x over previous
//
#include <hip/hip_runtime.h>
#include <stdint.h>

#define NB    64
#define NN    131072
#define NPTS  1024
#define WPB   4                     // workgroups per batch
#define TPB   1024                  // 16 waves
#define NWAVE (TPB / 64)
#define CHUNK (NN / WPB)            // 32768 points per wg
#define PPT   (CHUNK / TPB)         // 32 points per thread
#define RPTS  22                    // register-resident points/thread (j in [0,22))
#define LPTS  10                    // LDS-resident points/thread     (j in [22,32))
#define RPAIR (RPTS / 2)
#define LPAIR (LPTS / 2)

typedef float v2f __attribute__((ext_vector_type(2)));
typedef unsigned long long u64;

static __device__ __forceinline__ v2f vmin2(v2f a, v2f b) {
#if __has_builtin(__builtin_elementwise_min)
    return __builtin_elementwise_min(a, b);
#else
    v2f r; r.x = fminf(a.x, b.x); r.y = fminf(a.y, b.y); return r;
#endif
}

// ---------------- inter-wg protocol: stamped relaxed words, NO fences --------
// Per (batch, ring=k&7, rank): 4 u64 words, each self-validating:
//   w0 = x_bits<<32  | k          w1 = y_bits<<32 | k
//   w2 = z_bits<<32  | k          w3 = dist_bits<<32 | (NN-1-idx)<<10 | k
// u64 max on w3 == (max dist, then min idx) == jnp.argmax tie-break; same-round
// w3 share the k bits so ordering is exact. A reader consumes a word only if its
// stamp == k, so no publish-order requirements exist -> all atomics RELAXED
// (R4 showed acquire/release at agent scope = cache-maintenance storm, 118x).
// Ring-8 reuse is safe: a wg publishing round k+4 has observed every rank's
// k+3 publish, which implies every rank completed its round-(k+2) spin, hence
// all round-k reads finished long before slot k&7 is rewritten at k+8.
// Slots are zeroed once per launch (memset) so first-use never false-matches.

__global__ __launch_bounds__(TPB, 4) void fps_kernel(
    const float* __restrict__ pos,
    const int*   __restrict__ start_p,
    int*         __restrict__ out,
    u64*         __restrict__ slots)
{
#pragma clang fp contract(off)
    const int wg   = blockIdx.x;
    const int xcd  = wg & 7;            // heuristic: keep a batch's 4 wgs on one XCD
    const int sl   = wg >> 3;
    const int b    = xcd * 8 + (sl >> 2);
    const int r    = sl & 3;
    const int t    = threadIdx.x;
    const int lane = t & 63;
    const int wv   = t >> 6;

    const float* __restrict__ P  = pos + (size_t)b * NN * 3;
    const float* __restrict__ Pc = P + (size_t)r * CHUNK * 3;
    u64* __restrict__ bslots = slots + (size_t)b * 128;   // 8 rings * 4 ranks * 4 words

    // pair-packed LDS: coords of points (2l, 2l+1) adjacent -> ds_read_b64
    __shared__ float lx[LPAIR * TPB * 2];   // 40960 B
    __shared__ float ly[LPAIR * TPB * 2];
    __shared__ float lz[LPAIR * TPB * 2];
    __shared__ u64   wred[2][NWAVE];        // banked by k&1 (single-barrier loop)

    // ---- one-time staging: j<22 -> regs, j in [22,32) -> LDS (own-thread only) ----
    v2f rx[RPAIR], ry[RPAIR], rz[RPAIR];
#pragma unroll
    for (int p = 0; p < RPAIR; ++p) {
        const float* a = Pc + (size_t)(t + (2 * p) * TPB) * 3;
        const float* c = a + (size_t)TPB * 3;
        rx[p] = (v2f){a[0], c[0]};
        ry[p] = (v2f){a[1], c[1]};
        rz[p] = (v2f){a[2], c[2]};
    }
#pragma unroll
    for (int l = 0; l < LPAIR; ++l) {
        const float* a = Pc + (size_t)(t + (RPTS + 2 * l) * TPB) * 3;
        const float* c = a + (size_t)TPB * 3;
        const int idx = (l * TPB + t) * 2;
        lx[idx] = a[0]; lx[idx + 1] = c[0];   // same-thread RAW only: no barrier
        ly[idx] = a[1]; ly[idx + 1] = c[1];
        lz[idx] = a[2]; lz[idx + 1] = c[2];
    }

    const int start = start_p[0];
    float sx = P[(size_t)start * 3 + 0];
    float sy = P[(size_t)start * 3 + 1];
    float sz = P[(size_t)start * 3 + 2];
    if (r == 0 && t == 0) out[(size_t)b * NPTS] = start;

    v2f dist[PPT / 2];
#pragma unroll
    for (int p = 0; p < PPT / 2; ++p)
        dist[p] = (v2f){__builtin_inff(), __builtin_inff()};

    const int gbase = r * CHUNK;

    for (int k = 1; k < NPTS; ++k) {
        const int bank = k & 1;
        const int ring = k & 7;
        const v2f s0 = (v2f){sx, sx}, s1 = (v2f){sy, sy}, s2 = (v2f){sz, sz};
        float best = -1.0f;
        int   bi   = 0;

        // exact per-op rounding: (dx*dx + dy*dy) + dz*dz, contract off;
        // ascending j preserves first-occurrence argmax tie-break
#define PAIR_STEP(DP, PX, PY, PZ, I0)                                    \
        {                                                                \
            v2f dx = (PX) - s0, dy = (PY) - s1, dz = (PZ) - s2;          \
            v2f d  = (dx * dx + dy * dy) + dz * dz;                      \
            v2f nd = vmin2(dist[DP], d);                                 \
            dist[DP] = nd;                                               \
            if (nd.x > best) { best = nd.x; bi = (I0); }                 \
            if (nd.y > best) { best = nd.y; bi = (I0) + TPB; }           \
        }

#pragma unroll
        for (int p = 0; p < RPAIR; ++p)
            PAIR_STEP(p, rx[p], ry[p], rz[p], gbase + t + (2 * p) * TPB);
#pragma unroll
        for (int l = 0; l < LPAIR; ++l) {
            const int idx = (l * TPB + t) * 2;
            v2f px = *reinterpret_cast<const v2f*>(&lx[idx]);   // ds_read_b64
            v2f py = *reinterpret_cast<const v2f*>(&ly[idx]);
            v2f pz = *reinterpret_cast<const v2f*>(&lz[idx]);
            PAIR_STEP(RPAIR + l, px, py, pz, gbase + t + (RPTS + 2 * l) * TPB);
        }
#undef PAIR_STEP

        const u64 pk0 = ((u64)__float_as_uint(best) << 32) |
                        ((u64)(unsigned)(NN - 1 - bi) << 10) |
                        (unsigned)k;

        u64 pk = pk0;
#pragma unroll
        for (int o = 32; o >= 1; o >>= 1) {
            u64 q = __shfl_xor(pk, o, 64);
            if (q > pk) pk = q;
        }
        if (lane == 0) wred[bank][wv] = pk;
        __syncthreads();

        u64 v = wred[bank][lane & (NWAVE - 1)];
#pragma unroll
        for (int o = 1; o < NWAVE; o <<= 1) {
            u64 q = __shfl_xor(v, o, 64);
            if (q > v) v = q;
        }

        // Unique wg-winning thread (key embeds index) publishes coords + key.
        if (pk0 == v) {
            const int j = (bi - gbase - t) >> 10;       // TPB = 1024
            float wx, wy, wz;
            if (j < RPTS) {
                wx = 0.f; wy = 0.f; wz = 0.f;
#pragma unroll
                for (int p = 0; p < RPAIR; ++p) {
                    if (j == 2 * p)     { wx = rx[p].x; wy = ry[p].x; wz = rz[p].x; }
                    if (j == 2 * p + 1) { wx = rx[p].y; wy = ry[p].y; wz = rz[p].y; }
                }
            } else {
                const int jj  = j - RPTS;
                const int idx = ((jj >> 1) * TPB + t) * 2 + (jj & 1);
                wx = lx[idx]; wy = ly[idx]; wz = lz[idx];
            }
            u64* sb = bslots + ring * 16 + r * 4;
            __hip_atomic_store(sb + 0, ((u64)__float_as_uint(wx) << 32) | (unsigned)k,
                               __ATOMIC_RELAXED, __HIP_MEMORY_SCOPE_AGENT);
            __hip_atomic_store(sb + 1, ((u64)__float_as_uint(wy) << 32) | (unsigned)k,
                               __ATOMIC_RELAXED, __HIP_MEMORY_SCOPE_AGENT);
            __hip_atomic_store(sb + 2, ((u64)__float_as_uint(wz) << 32) | (unsigned)k,
                               __ATOMIC_RELAXED, __HIP_MEMORY_SCOPE_AGENT);
            __hip_atomic_store(sb + 3, pk0,
                               __ATOMIC_RELAXED, __HIP_MEMORY_SCOPE_AGENT);
        }

        // all lanes spin on rank (lane&3)'s key; every word self-validated by stamp
        const u64* sp = bslots + ring * 16 + (size_t)(lane & 3) * 4;
        u64 w3;
        for (;;) {
            w3 = __hip_atomic_load(sp + 3, __ATOMIC_RELAXED, __HIP_MEMORY_SCOPE_AGENT);
            if ((unsigned)(w3 & 1023ull) == (unsigned)k) break;
            __builtin_amdgcn_s_sleep(1);
        }
        u64 w0, w1, w2;
        for (;;) {
            w0 = __hip_atomic_load(sp + 0, __ATOMIC_RELAXED, __HIP_MEMORY_SCOPE_AGENT);
            if ((unsigned)w0 == (unsigned)k) break;
        }
        for (;;) {
            w1 = __hip_atomic_load(sp + 1, __ATOMIC_RELAXED, __HIP_MEMORY_SCOPE_AGENT);
            if ((unsigned)w1 == (unsigned)k) break;
        }
        for (;;) {
            w2 = __hip_atomic_load(sp + 2, __ATOMIC_RELAXED, __HIP_MEMORY_SCOPE_AGENT);
            if ((unsigned)w2 == (unsigned)k) break;
        }

        // combine the 4 ranks: key-compare butterfly carrying the coord payload
#pragma unroll
        for (int o = 1; o <= 2; o <<= 1) {
            u64 q3 = __shfl_xor(w3, o, 64);
            u64 q0 = __shfl_xor(w0, o, 64);
            u64 q1 = __shfl_xor(w1, o, 64);
            u64 q2 = __shfl_xor(w2, o, 64);
            if (q3 > w3) { w3 = q3; w0 = q0; w1 = q1; w2 = q2; }
        }

        const int widx = NN - 1 - (int)((w3 >> 10) & 0x1FFFFull);
        if (r == 0 && t == 0) out[(size_t)b * NPTS + k] = widx;
        sx = __uint_as_float((unsigned)(w0 >> 32));
        sy = __uint_as_float((unsigned)(w1 >> 32));
        sz = __uint_as_float((unsigned)(w2 >> 32));
    }
}

extern "C" void kernel_launch(void* const* d_in, const int* in_sizes, int n_in,
                              void* d_out, int out_size, void* d_ws, size_t ws_size,
                              hipStream_t stream)
{
    const float* pos     = (const float*)d_in[0];
    const int*   start_p = (const int*)d_in[1];
    int*         out     = (int*)d_out;
    u64*         slots   = (u64*)d_ws;

    // 64 batches x 8 rings x 4 ranks x 4 words x 8 B = 64 KB; zeroed so
    // first-use stamps (k>=1) can never false-match.
    hipMemsetAsync(d_ws, 0, (size_t)NB * 128 * sizeof(u64), stream);

    void* args[] = { (void*)&pos, (void*)&start_p, (void*)&out, (void*)&slots };
    hipError_t e = hipLaunchCooperativeKernel((const void*)fps_kernel,
                                              dim3(NB * WPB), dim3(TPB),
                                              args, 0, stream);
    if (e != hipSuccess) {
        // 256 blocks of 1024 thr = 1 block/CU: de-facto co-resident; same protocol.
        fps_kernel<<<dim3(NB * WPB), dim3(TPB), 0, stream>>>(pos, start_p, out, slots);
    }
}

// Round 6
// 4274.311 us; speedup vs baseline: 121.9381x; 2.7971x over previous
//
#include <hip/hip_runtime.h>
#include <stdint.h>

#define NB    64
#define NN    131072
#define NPTS  1024
#define WPB   4                     // workgroups per batch
#define TPB   1024                  // 16 waves
#define NWAVE (TPB / 64)
#define CHUNK (NN / WPB)            // 32768 points per wg
#define PPT   (CHUNK / TPB)         // 32 points per thread
#define RPTS  20                    // register-resident points/thread (j in [0,20))
#define LPTS  12                    // LDS-resident points/thread     (j in [20,32))
#define RPAIR (RPTS / 2)
#define LPAIR (LPTS / 2)

typedef float v2f __attribute__((ext_vector_type(2)));
typedef unsigned long long u64;

static __device__ __forceinline__ v2f vmin2(v2f a, v2f b) {
#if __has_builtin(__builtin_elementwise_min)
    return __builtin_elementwise_min(a, b);
#else
    v2f r; r.x = fminf(a.x, b.x); r.y = fminf(a.y, b.y); return r;
#endif
}

// ---------------- inter-wg protocol (R3-proven): relaxed + cold slots --------
// One u64 slot per (batch, round k, rank): [dist_bits:32 | ~idx:32].
//   u64 max == (max dist, then min idx) == jnp.argmax first-occurrence.
//   ~idx != 0, so nonzero doubles as the publish flag (slots memset to 0).
// KEY HW LESSON (R4/R5): use RELAXED atomics only (acquire/release at agent
// scope = cache-maintenance storm, 118x), and NEVER reuse a spin address
// within a launch (a reused line can be cached stale under relaxed loads;
// per-round-unique slots make every spin's first touch a cold fetch from the
// coherence point). 2 MB of slots, memset once per launch.

__global__ __launch_bounds__(TPB)
__attribute__((amdgpu_waves_per_eu(4, 4)))   // exact 4 waves/EU -> 128-VGPR budget, no heuristic under-allocation
void fps_kernel(
    const float* __restrict__ pos,
    const int*   __restrict__ start_p,
    int*         __restrict__ out,
    u64*         __restrict__ slots)
{
#pragma clang fp contract(off)
    const int wg   = blockIdx.x;
    const int xcd  = wg & 7;            // heuristic: keep a batch's 4 wgs on one XCD
    const int sl   = wg >> 3;
    const int b    = xcd * 8 + (sl >> 2);
    const int r    = sl & 3;
    const int t    = threadIdx.x;
    const int lane = t & 63;
    const int wv   = t >> 6;

    const float* __restrict__ P  = pos + (size_t)b * NN * 3;
    const float* __restrict__ Pc = P + (size_t)r * CHUNK * 3;
    u64* __restrict__ bslots = slots + (size_t)b * NPTS * WPB;

    // pair-packed LDS: coords of points (2l, 2l+1) adjacent -> ds_read_b64
    __shared__ float lx[LPAIR * TPB * 2];   // 49152 B
    __shared__ float ly[LPAIR * TPB * 2];
    __shared__ float lz[LPAIR * TPB * 2];   // 147456 B total
    __shared__ u64   wred[2][NWAVE];        // banked by k&1 (single-barrier loop)

    // ---- one-time staging: j<20 -> regs, j in [20,32) -> LDS (own-thread only) ----
    v2f rx[RPAIR], ry[RPAIR], rz[RPAIR];
#pragma unroll
    for (int p = 0; p < RPAIR; ++p) {
        const float* a = Pc + (size_t)(t + (2 * p) * TPB) * 3;
        const float* c = a + (size_t)TPB * 3;
        rx[p] = (v2f){a[0], c[0]};
        ry[p] = (v2f){a[1], c[1]};
        rz[p] = (v2f){a[2], c[2]};
    }
#pragma unroll
    for (int l = 0; l < LPAIR; ++l) {
        const float* a = Pc + (size_t)(t + (RPTS + 2 * l) * TPB) * 3;
        const float* c = a + (size_t)TPB * 3;
        const int idx = (l * TPB + t) * 2;
        lx[idx] = a[0]; lx[idx + 1] = c[0];   // same-thread RAW only: no barrier
        ly[idx] = a[1]; ly[idx + 1] = c[1];
        lz[idx] = a[2]; lz[idx + 1] = c[2];
    }

    const int start = start_p[0];
    float sx = P[(size_t)start * 3 + 0];
    float sy = P[(size_t)start * 3 + 1];
    float sz = P[(size_t)start * 3 + 2];
    if (r == 0 && t == 0) out[(size_t)b * NPTS] = start;

    v2f dist[PPT / 2];
#pragma unroll
    for (int p = 0; p < PPT / 2; ++p)
        dist[p] = (v2f){__builtin_inff(), __builtin_inff()};

    const int gbase = r * CHUNK;

    for (int k = 1; k < NPTS; ++k) {
        const int bank = k & 1;
        const v2f s0 = (v2f){sx, sx}, s1 = (v2f){sy, sy}, s2 = (v2f){sz, sz};
        float best = -1.0f;
        int   bi   = 0;

        // exact per-op rounding: (dx*dx + dy*dy) + dz*dz, contract off;
        // ascending j preserves first-occurrence argmax tie-break
#define PAIR_STEP(DP, PX, PY, PZ, I0)                                    \
        {                                                                \
            v2f dx = (PX) - s0, dy = (PY) - s1, dz = (PZ) - s2;          \
            v2f d  = (dx * dx + dy * dy) + dz * dz;                      \
            v2f nd = vmin2(dist[DP], d);                                 \
            dist[DP] = nd;                                               \
            if (nd.x > best) { best = nd.x; bi = (I0); }                 \
            if (nd.y > best) { best = nd.y; bi = (I0) + TPB; }           \
        }

#pragma unroll
        for (int p = 0; p < RPAIR; ++p)
            PAIR_STEP(p, rx[p], ry[p], rz[p], gbase + t + (2 * p) * TPB);
#pragma unroll
        for (int l = 0; l < LPAIR; ++l) {
            const int idx = (l * TPB + t) * 2;
            v2f px = *reinterpret_cast<const v2f*>(&lx[idx]);   // ds_read_b64
            v2f py = *reinterpret_cast<const v2f*>(&ly[idx]);
            v2f pz = *reinterpret_cast<const v2f*>(&lz[idx]);
            PAIR_STEP(RPAIR + l, px, py, pz, gbase + t + (RPTS + 2 * l) * TPB);
        }
#undef PAIR_STEP

        u64 pk = ((u64)__float_as_uint(best) << 32) | (unsigned)~bi;

        // 64-lane wave max-reduce
#pragma unroll
        for (int o = 32; o >= 1; o >>= 1) {
            u64 q = __shfl_xor(pk, o, 64);
            if (q > pk) pk = q;
        }
        if (lane == 0) wred[bank][wv] = pk;
        __syncthreads();

        // every wave reduces the 16 wave-partials itself (no 2nd barrier)
        u64 v = wred[bank][lane & (NWAVE - 1)];
#pragma unroll
        for (int o = 1; o < NWAVE; o <<= 1) {
            u64 q = __shfl_xor(v, o, 64);
            if (q > v) v = q;
        }
        if (t == 0)
            __hip_atomic_store(&bslots[(size_t)k * WPB + r], v,
                               __ATOMIC_RELAXED, __HIP_MEMORY_SCOPE_AGENT);

        // all lanes spin on rank (lane&3)'s slot — cold line, relaxed only
        const u64* sp = &bslots[(size_t)k * WPB + (lane & 3)];
        u64 g;
        for (;;) {
            g = __hip_atomic_load(sp, __ATOMIC_RELAXED, __HIP_MEMORY_SCOPE_AGENT);
            if (g) break;
            __builtin_amdgcn_s_sleep(1);
        }
#pragma unroll
        for (int o = 1; o <= 2; o <<= 1) {
            u64 q = __shfl_xor(g, o, 64);
            if (q > g) g = q;
        }
        const int widx = (int)~(unsigned)g;
        if (r == 0 && t == 0) out[(size_t)b * NPTS + k] = widx;
        // uniform address across lanes: single transaction, L2/L3-hot
        sx = P[(size_t)widx * 3 + 0];
        sy = P[(size_t)widx * 3 + 1];
        sz = P[(size_t)widx * 3 + 2];
    }
}

extern "C" void kernel_launch(void* const* d_in, const int* in_sizes, int n_in,
                              void* d_out, int out_size, void* d_ws, size_t ws_size,
                              hipStream_t stream)
{
    const float* pos     = (const float*)d_in[0];
    const int*   start_p = (const int*)d_in[1];
    int*         out     = (int*)d_out;
    u64*         slots   = (u64*)d_ws;

    // 64 batches x 1024 rounds x 4 ranks x 8 B = 2 MB; zeroed so nonzero == published
    hipMemsetAsync(d_ws, 0, (size_t)NB * NPTS * WPB * sizeof(u64), stream);

    void* args[] = { (void*)&pos, (void*)&start_p, (void*)&out, (void*)&slots };
    hipError_t e = hipLaunchCooperativeKernel((const void*)fps_kernel,
                                              dim3(NB * WPB), dim3(TPB),
                                              args, 0, stream);
    if (e != hipSuccess) {
        // 256 blocks of 1024 thr = 1 block/CU: de-facto co-resident; same protocol.
        fps_kernel<<<dim3(NB * WPB), dim3(TPB), 0, stream>>>(pos, start_p, out, slots);
    }
}